// Round 6
// baseline (1763.915 us; speedup 1.0000x reference)
//
#include <hip/hip_runtime.h>

// ARMA GCN (K=2, two layers) on MI355X — MEGAKERNEL version.
//   Layer1: h = mean_k relu( A@(x@iw1_k) + x@rw1_k + b1_k )   [N,16]
//   Layer2: out = mean_k relu( (A@h)@iw2_k + h@rw2_k + b2_k ) [N,40]
// One persistent kernel (grid=1024, 4 blocks/CU guaranteed via
// __launch_bounds__(256,4); LDS 10.6KB/block) with device-scope software
// barriers. Phases:
//   P1: binA (fixed-capacity radix partition) || wsplit || zero dummy rows
//   P2: binB (exact 8-padded CSR per 512-bucket) || gemm1 (MFMA, writes
//       UNSCALED H1 fp32 + R fp32 -> no dinv dependency, enables overlap)
//   P3: scale H1*dinv -> Hs bf16 (single rounding)
//   P4: prop1 (8-deep pipelined 16B gathers, int4 index loads, tail-free)
//   P5: prop2 (8B gathers)
//   P6: final small GEMM
// Barriers: one-shot counters (memset per iteration), agent-scope
// atomics + __threadfence() both sides for cross-XCD L1/L2 coherence.

#define TB 256
#define CHA 4096  // edges per block-chunk in binA
#define NG 1024   // persistent grid (4 blocks/CU x 256 CU)

typedef __attribute__((ext_vector_type(8))) short bf8;
typedef __attribute__((ext_vector_type(4))) float f4;

__device__ inline unsigned short f2bf_rne(float f) {
  unsigned int u = __float_as_uint(f);
  unsigned int r = u + 0x7fffu + ((u >> 16) & 1u);
  return (unsigned short)(r >> 16);
}
__device__ inline float bf2f(unsigned short h) {
  return __uint_as_float(((unsigned int)h) << 16);
}
__device__ inline float bflo(unsigned int u) { return __uint_as_float(u << 16); }
__device__ inline float bfhi(unsigned int u) { return __uint_as_float(u & 0xffff0000u); }
__device__ inline unsigned int bfpack(float lo, float hi) {
  return (unsigned int)f2bf_rne(lo) | ((unsigned int)f2bf_rne(hi) << 16);
}

#define ACC8(v)                                   \
  do {                                            \
    a[0] += bflo((v).x); a[1] += bfhi((v).x);     \
    a[2] += bflo((v).y); a[3] += bfhi((v).y);     \
    a[4] += bflo((v).z); a[5] += bfhi((v).z);     \
    a[6] += bflo((v).w); a[7] += bfhi((v).w);     \
  } while (0)

#define ACC4(v)                                   \
  do {                                            \
    a[0] += bflo((v).x); a[1] += bfhi((v).x);     \
    a[2] += bflo((v).y); a[3] += bfhi((v).y);     \
  } while (0)

// Device-scope one-shot barrier. All NG blocks must be co-resident
// (guaranteed: launch_bounds(256,4) -> 4 blocks/CU, grid = 4*256).
__device__ inline void gbar(int* bar, int G) {
  __syncthreads();
  __threadfence();  // release: drain this block's writes past L1 (wbl2)
  if (threadIdx.x == 0) {
    __hip_atomic_fetch_add(bar, 1, __ATOMIC_ACQ_REL, __HIP_MEMORY_SCOPE_AGENT);
    while (__hip_atomic_load(bar, __ATOMIC_RELAXED, __HIP_MEMORY_SCOPE_AGENT) < G)
      __builtin_amdgcn_s_sleep(2);
  }
  __syncthreads();
  __threadfence();  // acquire: invalidate L1/L2 so fresh data is read
}

__global__ __launch_bounds__(TB, 4) void k_mega(
    const float* __restrict__ x, const int* __restrict__ src,
    const int* __restrict__ dst, const float* __restrict__ iw1,
    const float* __restrict__ rw1, const float* __restrict__ b1,
    const float* __restrict__ iw2, const float* __restrict__ rw2,
    const float* __restrict__ b2, int* __restrict__ ccur,
    int* __restrict__ bars, unsigned int* __restrict__ epairs,
    int* __restrict__ srcs, int* __restrict__ degi, int* __restrict__ offsets,
    float* __restrict__ dinv, short* __restrict__ Whi, short* __restrict__ Wlo,
    float* __restrict__ H1f, float* __restrict__ R,
    unsigned short* __restrict__ Hs, float* __restrict__ hbuf,
    unsigned short* __restrict__ hs, float* __restrict__ Ah,
    float* __restrict__ out, int N, int E, int NC, int cap, int scap) {
  __shared__ union {
    struct { int cnt[256]; int gb[256]; } ba;
    struct { int cnt[512]; int pre[512]; } bb;
    struct { float w_iw[1280]; float w_rw[1280]; float w_b[80]; } fin;
  } sm;

  const int bid = blockIdx.x;
  const int tid = threadIdx.x;
  const int G = gridDim.x;
  const int NBLK = (E + CHA - 1) / CHA;
  const int NT = (N + 63) >> 6;          // gemm1 64-row tiles
  const int PG = ((N * 4) + TB - 1) / TB;  // prop thread-groups

  // ===== Phase 1: binA (blocks 0..NBLK-1)  ||  wsplit (blocks NBLK..) =====
  if (bid < NBLK) {
    sm.ba.cnt[tid] = 0;
    __syncthreads();
    int e0 = bid * CHA;
    int e1 = min(e0 + CHA, E);
    for (int e = e0 + tid; e < e1; e += TB) atomicAdd(&sm.ba.cnt[dst[e] >> 9], 1);
    __syncthreads();
    int c = sm.ba.cnt[tid];
    if (c > 0) sm.ba.gb[tid] = tid * cap + atomicAdd(&ccur[tid], c);
    __syncthreads();
    sm.ba.cnt[tid] = 0;
    __syncthreads();
    for (int e = e0 + tid; e < e1; e += TB) {
      int dv = dst[e];
      int b = dv >> 9;
      int r = atomicAdd(&sm.ba.cnt[b], 1);
      epairs[sm.ba.gb[b] + r] = ((unsigned int)src[e] << 9) | (unsigned int)(dv & 511);
    }
  } else {
    for (int w = bid - NBLK; w < 128; w += G - NBLK) {
      int idx = w * TB + tid;
      if (idx < 32) Hs[(size_t)N * 32 + idx] = 0;  // dummy row (padded edges)
      if (idx < 16) hs[(size_t)N * 16 + idx] = 0;
      int j = idx & 7;
      int l = (idx >> 3) & 63;
      int t = (idx >> 9) & 3;
      int c = idx >> 11;
      int k = c * 32 + (l >> 4) * 8 + j;
      int n = t * 16 + (l & 15);
      float wv;
      if (n < 16) wv = iw1[k * 16 + n];
      else if (n < 32) wv = iw1[8192 + k * 16 + (n - 16)];
      else if (n < 48) wv = rw1[k * 16 + (n - 32)];
      else wv = rw1[8192 + k * 16 + (n - 48)];
      unsigned short hh = f2bf_rne(wv);
      float res = wv - bf2f(hh);
      Whi[idx] = (short)hh;
      Wlo[idx] = (short)f2bf_rne(res);
    }
  }
  gbar(&bars[0], G);

  // ===== Phase 2: binB (blocks 0..NC-1)  ||  gemm1 (blocks NC..) ==========
  if (bid < NC) {
    int b = bid;
    int n0 = b << 9;
    int beg = b * cap;
    int end = beg + ccur[b];
    int pbase = b * scap;
    int i0 = tid, i1 = tid + 256;
    sm.bb.cnt[i0] = 0; sm.bb.cnt[i1] = 0;
    __syncthreads();
    for (int e = beg + tid; e < end; e += TB)
      atomicAdd(&sm.bb.cnt[epairs[e] & 511u], 1);
    __syncthreads();
    int pd0 = (sm.bb.cnt[i0] + 7) & ~7;
    int pd1 = (sm.bb.cnt[i1] + 7) & ~7;
    sm.bb.pre[i0] = pd0; sm.bb.pre[i1] = pd1;
    __syncthreads();
    for (int d = 1; d < 512; d <<= 1) {
      int t0 = (i0 >= d) ? sm.bb.pre[i0 - d] : 0;
      int t1 = (i1 >= d) ? sm.bb.pre[i1 - d] : 0;
      __syncthreads();
      sm.bb.pre[i0] += t0; sm.bb.pre[i1] += t1;
      __syncthreads();
    }
    int s0 = sm.bb.pre[i0] - pd0;
    int s1 = sm.bb.pre[i1] - pd1;
    if (n0 + i0 < N) {
      int c0 = sm.bb.cnt[i0];
      degi[n0 + i0] = c0;
      offsets[n0 + i0] = pbase + s0;
      dinv[n0 + i0] = c0 > 0 ? rsqrtf((float)c0) : 0.0f;
    }
    if (n0 + i1 < N) {
      int c1 = sm.bb.cnt[i1];
      degi[n0 + i1] = c1;
      offsets[n0 + i1] = pbase + s1;
      dinv[n0 + i1] = c1 > 0 ? rsqrtf((float)c1) : 0.0f;
    }
    __syncthreads();
    sm.bb.cnt[i0] = s0; sm.bb.cnt[i1] = s1;  // scatter cursors
    __syncthreads();
    for (int e = beg + tid; e < end; e += TB) {
      unsigned int p = epairs[e];
      int pos = atomicAdd(&sm.bb.cnt[p & 511u], 1);
      srcs[pbase + pos] = (int)(p >> 9);
    }
    __syncthreads();
    for (int j = sm.bb.cnt[i0]; j < sm.bb.pre[i0]; ++j) srcs[pbase + j] = N;
    for (int j = sm.bb.cnt[i1]; j < sm.bb.pre[i1]; ++j) srcs[pbase + j] = N;
  } else {
    int lane = tid & 63;
    int wave = tid >> 6;
    int m = lane & 15, quad = lane >> 4;
    for (int tile = bid - NC; tile < NT; tile += G - NC) {
      int row0 = tile * 64 + wave * 16;
      int r = row0 + m;
      bool rv = (r < N);
      const float* xr = x + (size_t)r * 512;
      f4 acc[4];
#pragma unroll
      for (int t = 0; t < 4; t++) acc[t] = (f4){0.f, 0.f, 0.f, 0.f};
      for (int c = 0; c < 16; ++c) {
        float xv[8];
        if (rv) {
          f4 a0 = *(const f4*)(xr + c * 32 + quad * 8);
          f4 a1 = *(const f4*)(xr + c * 32 + quad * 8 + 4);
          xv[0] = a0.x; xv[1] = a0.y; xv[2] = a0.z; xv[3] = a0.w;
          xv[4] = a1.x; xv[5] = a1.y; xv[6] = a1.z; xv[7] = a1.w;
        } else {
#pragma unroll
          for (int j = 0; j < 8; ++j) xv[j] = 0.f;
        }
        bf8 ahi, alo;
#pragma unroll
        for (int j = 0; j < 8; ++j) {
          unsigned short hh = f2bf_rne(xv[j]);
          float res = xv[j] - bf2f(hh);
          ahi[j] = (short)hh;
          alo[j] = (short)f2bf_rne(res);
        }
        const short* wb = Whi + ((size_t)(c * 4) * 64 + lane) * 8;
        const short* wl = Wlo + ((size_t)(c * 4) * 64 + lane) * 8;
#pragma unroll
        for (int t = 0; t < 4; ++t) {
          bf8 bh = *(const bf8*)(wb + t * 512);
          bf8 bl = *(const bf8*)(wl + t * 512);
          acc[t] = __builtin_amdgcn_mfma_f32_16x16x32_bf16(ahi, bh, acc[t], 0, 0, 0);
          acc[t] = __builtin_amdgcn_mfma_f32_16x16x32_bf16(alo, bh, acc[t], 0, 0, 0);
          acc[t] = __builtin_amdgcn_mfma_f32_16x16x32_bf16(ahi, bl, acc[t], 0, 0, 0);
        }
      }
      // C/D layout: col = t*16+m, row = quad*4+g. Unscaled outputs.
#pragma unroll
      for (int t = 0; t < 4; ++t) {
#pragma unroll
        for (int g = 0; g < 4; ++g) {
          int ro = row0 + quad * 4 + g;
          if (ro < N) {
            if (t < 2)
              H1f[(size_t)ro * 32 + t * 16 + m] = acc[t][g];
            else
              R[(size_t)ro * 32 + (t - 2) * 16 + m] = acc[t][g];
          }
        }
      }
    }
  }
  gbar(&bars[1], G);

  // ===== Phase 3: Hs = bf16(H1f * dinv)  (single rounding) ================
  for (int i = bid * TB + tid; i < N * 4; i += G * TB) {
    int n = i >> 2;
    int o = (i & 3) * 8;
    float d = dinv[n];
    f4 a0 = *(const f4*)(H1f + (size_t)n * 32 + o);
    f4 a1 = *(const f4*)(H1f + (size_t)n * 32 + o + 4);
    uint4 ob;
    ob.x = bfpack(a0.x * d, a0.y * d);
    ob.y = bfpack(a0.z * d, a0.w * d);
    ob.z = bfpack(a1.x * d, a1.y * d);
    ob.w = bfpack(a1.z * d, a1.w * d);
    *(uint4*)(Hs + (size_t)n * 32 + o) = ob;
  }
  gbar(&bars[2], G);

  // ===== Phase 4: prop1 ====================================================
  for (int g = bid; g < PG; g += G) {
    int t2 = g * TB + tid;
    int q = t2 & 3;
    int n = t2 >> 2;
    if (n < N) {
      int beg = offsets[n], cnt = degi[n];
      int pdeg = (cnt + 7) & ~7;
      const unsigned short* Hq = Hs + q * 8;
      float a[8];
#pragma unroll
      for (int j = 0; j < 8; j++) a[j] = 0.f;
      if (pdeg) {
        int4 sa = *(const int4*)(srcs + beg);
        int4 sb = *(const int4*)(srcs + beg + 4);
        int i = 0;
        for (; i + 16 <= pdeg; i += 8) {
          uint4 v0 = *(const uint4*)(Hq + (size_t)sa.x * 32);
          uint4 v1 = *(const uint4*)(Hq + (size_t)sa.y * 32);
          uint4 v2 = *(const uint4*)(Hq + (size_t)sa.z * 32);
          uint4 v3 = *(const uint4*)(Hq + (size_t)sa.w * 32);
          uint4 v4 = *(const uint4*)(Hq + (size_t)sb.x * 32);
          uint4 v5 = *(const uint4*)(Hq + (size_t)sb.y * 32);
          uint4 v6 = *(const uint4*)(Hq + (size_t)sb.z * 32);
          uint4 v7 = *(const uint4*)(Hq + (size_t)sb.w * 32);
          sa = *(const int4*)(srcs + beg + i + 8);
          sb = *(const int4*)(srcs + beg + i + 12);
          ACC8(v0); ACC8(v1); ACC8(v2); ACC8(v3);
          ACC8(v4); ACC8(v5); ACC8(v6); ACC8(v7);
        }
        uint4 v0 = *(const uint4*)(Hq + (size_t)sa.x * 32);
        uint4 v1 = *(const uint4*)(Hq + (size_t)sa.y * 32);
        uint4 v2 = *(const uint4*)(Hq + (size_t)sa.z * 32);
        uint4 v3 = *(const uint4*)(Hq + (size_t)sa.w * 32);
        uint4 v4 = *(const uint4*)(Hq + (size_t)sb.x * 32);
        uint4 v5 = *(const uint4*)(Hq + (size_t)sb.y * 32);
        uint4 v6 = *(const uint4*)(Hq + (size_t)sb.z * 32);
        uint4 v7 = *(const uint4*)(Hq + (size_t)sb.w * 32);
        ACC8(v0); ACC8(v1); ACC8(v2); ACC8(v3);
        ACC8(v4); ACC8(v5); ACC8(v6); ACC8(v7);
      }
      float dvn = dinv[n];
      f4 r0 = *(const f4*)(R + (size_t)n * 32 + q * 8);
      f4 r1 = *(const f4*)(R + (size_t)n * 32 + q * 8 + 4);
      float rr[8] = {r0.x, r0.y, r0.z, r0.w, r1.x, r1.y, r1.z, r1.w};
      float vv[8];
#pragma unroll
      for (int j = 0; j < 8; j++) {
        int f = q * 8 + j;
        vv[j] = fmaxf(a[j] * dvn + rr[j] + b1[f], 0.f);
      }
      float pv[8];
#pragma unroll
      for (int j = 0; j < 8; j++) pv[j] = __shfl_xor(vv[j], 2);
      if (q < 2) {
        float hv[8];
#pragma unroll
        for (int j = 0; j < 8; j++) hv[j] = 0.5f * (vv[j] + pv[j]);
        f4 o0 = {hv[0], hv[1], hv[2], hv[3]};
        f4 o1 = {hv[4], hv[5], hv[6], hv[7]};
        *(f4*)(hbuf + (size_t)n * 16 + q * 8) = o0;
        *(f4*)(hbuf + (size_t)n * 16 + q * 8 + 4) = o1;
        uint4 ob;
        ob.x = bfpack(hv[0] * dvn, hv[1] * dvn);
        ob.y = bfpack(hv[2] * dvn, hv[3] * dvn);
        ob.z = bfpack(hv[4] * dvn, hv[5] * dvn);
        ob.w = bfpack(hv[6] * dvn, hv[7] * dvn);
        *(uint4*)(hs + (size_t)n * 16 + q * 8) = ob;
      }
    }
  }
  gbar(&bars[3], G);

  // ===== Phase 5: prop2 ====================================================
  for (int g = bid; g < PG; g += G) {
    int t2 = g * TB + tid;
    int q = t2 & 3;
    int n = t2 >> 2;
    if (n < N) {
      int beg = offsets[n], cnt = degi[n];
      int pdeg = (cnt + 7) & ~7;
      const unsigned short* Hq = hs + q * 4;
      float a[4] = {0.f, 0.f, 0.f, 0.f};
      if (pdeg) {
        int4 sa = *(const int4*)(srcs + beg);
        int4 sb = *(const int4*)(srcs + beg + 4);
        int i = 0;
        for (; i + 16 <= pdeg; i += 8) {
          uint2 v0 = *(const uint2*)(Hq + (size_t)sa.x * 16);
          uint2 v1 = *(const uint2*)(Hq + (size_t)sa.y * 16);
          uint2 v2 = *(const uint2*)(Hq + (size_t)sa.z * 16);
          uint2 v3 = *(const uint2*)(Hq + (size_t)sa.w * 16);
          uint2 v4 = *(const uint2*)(Hq + (size_t)sb.x * 16);
          uint2 v5 = *(const uint2*)(Hq + (size_t)sb.y * 16);
          uint2 v6 = *(const uint2*)(Hq + (size_t)sb.z * 16);
          uint2 v7 = *(const uint2*)(Hq + (size_t)sb.w * 16);
          sa = *(const int4*)(srcs + beg + i + 8);
          sb = *(const int4*)(srcs + beg + i + 12);
          ACC4(v0); ACC4(v1); ACC4(v2); ACC4(v3);
          ACC4(v4); ACC4(v5); ACC4(v6); ACC4(v7);
        }
        uint2 v0 = *(const uint2*)(Hq + (size_t)sa.x * 16);
        uint2 v1 = *(const uint2*)(Hq + (size_t)sa.y * 16);
        uint2 v2 = *(const uint2*)(Hq + (size_t)sa.z * 16);
        uint2 v3 = *(const uint2*)(Hq + (size_t)sa.w * 16);
        uint2 v4 = *(const uint2*)(Hq + (size_t)sb.x * 16);
        uint2 v5 = *(const uint2*)(Hq + (size_t)sb.y * 16);
        uint2 v6 = *(const uint2*)(Hq + (size_t)sb.z * 16);
        uint2 v7 = *(const uint2*)(Hq + (size_t)sb.w * 16);
        ACC4(v0); ACC4(v1); ACC4(v2); ACC4(v3);
        ACC4(v4); ACC4(v5); ACC4(v6); ACC4(v7);
      }
      float dvn = dinv[n];
      f4 o = {a[0] * dvn, a[1] * dvn, a[2] * dvn, a[3] * dvn};
      *(f4*)(Ah + (size_t)n * 16 + q * 4) = o;
    }
  }
  gbar(&bars[4], G);

  // ===== Phase 6: final ====================================================
  for (int i = tid; i < 1280; i += TB) {
    sm.fin.w_iw[i] = iw2[i];
    sm.fin.w_rw[i] = rw2[i];
  }
  for (int i = tid; i < 80; i += TB) sm.fin.w_b[i] = b2[i];
  __syncthreads();
  for (int idx = bid * TB + tid; idx < N * 40; idx += G * TB) {
    int n = idx / 40;
    int o = idx - n * 40;
    float a[16], hr[16];
#pragma unroll
    for (int f = 0; f < 16; f++) {
      a[f] = Ah[(size_t)n * 16 + f];
      hr[f] = hbuf[(size_t)n * 16 + f];
    }
    float res = 0.f;
#pragma unroll
    for (int k = 0; k < 2; k++) {
      float s = sm.fin.w_b[k * 40 + o];
#pragma unroll
      for (int f = 0; f < 16; f++) {
        s += a[f] * sm.fin.w_iw[(k * 16 + f) * 40 + o];
        s += hr[f] * sm.fin.w_rw[(k * 16 + f) * 40 + o];
      }
      res += fmaxf(s, 0.f);
    }
    out[idx] = 0.5f * res;
  }
}

extern "C" void kernel_launch(void* const* d_in, const int* in_sizes, int n_in,
                              void* d_out, int out_size, void* d_ws, size_t ws_size,
                              hipStream_t stream) {
  const float* x = (const float*)d_in[0];
  const int* ei = (const int*)d_in[1];
  const float* iw1 = (const float*)d_in[2];
  const float* rw1 = (const float*)d_in[3];
  const float* b1 = (const float*)d_in[4];
  const float* iw2 = (const float*)d_in[5];
  const float* rw2 = (const float*)d_in[6];
  const float* b2 = (const float*)d_in[7];
  float* out = (float*)d_out;

  const int N = in_sizes[0] / 512;
  const int E = in_sizes[1] / 2;
  const int* src = ei;
  const int* dst = ei + E;
  const int NC = (N + 511) >> 9;  // coarse buckets (196 for N=100k)

  // fixed bucket capacity: mean + ~12% slack (sigma ~ sqrt(mean)), 8-aligned
  int mean = (E + NC - 1) / NC;
  int cap = (mean + mean / 8 + 256 + 7) & ~7;
  int scap = cap + 7 * 512;  // room for 8-padding (max 7 dummies/node)

  char* base = (char*)d_ws;
  size_t off = 0;
  auto alloc = [&](size_t bytes) -> void* {
    off = (off + 255) & ~(size_t)255;
    void* p = base + off;
    off += bytes;
    return p;
  };
  int* degi = (int*)alloc((size_t)N * 4);
  float* dinv = (float*)alloc((size_t)N * 4);
  int* offsets = (int*)alloc((size_t)N * 4);
  int* cz = (int*)alloc(264 * 4);  // ccur[256] + bars[8], zeroed together
  int* ccur = cz;
  int* bars = cz + 256;
  unsigned int* epairs = (unsigned int*)alloc((size_t)NC * cap * 4);
  int* srcs = (int*)alloc((size_t)NC * scap * 4);
  unsigned short* Hs = (unsigned short*)alloc((size_t)(N + 1) * 32 * 2);
  float* H1f = (float*)alloc((size_t)N * 32 * 4);
  float* R = (float*)alloc((size_t)N * 32 * 4);
  float* hbuf = (float*)alloc((size_t)N * 16 * 4);
  unsigned short* hs = (unsigned short*)alloc((size_t)(N + 1) * 16 * 2);
  float* Ah = (float*)alloc((size_t)N * 16 * 4);
  short* Whi = (short*)alloc(32768 * 2);
  short* Wlo = (short*)alloc(32768 * 2);
  (void)ws_size;

  hipMemsetAsync(cz, 0, 264 * 4, stream);
  k_mega<<<NG, TB, 0, stream>>>(x, src, dst, iw1, rw1, b1, iw2, rw2, b2,
                                ccur, bars, epairs, srcs, degi, offsets, dinv,
                                Whi, Wlo, H1f, R, Hs, hbuf, hs, Ah, out,
                                N, E, NC, cap, scap);
}